// Round 1
// baseline (1050.659 us; speedup 1.0000x reference)
//
#include <hip/hip_runtime.h>
#include <hip/hip_bf16.h>
#include <stdint.h>

typedef unsigned short u16;
typedef unsigned int u32;

typedef __attribute__((__ext_vector_type__(8))) short short8;
typedef __attribute__((__ext_vector_type__(4))) float float4v;
typedef __attribute__((__ext_vector_type__(16))) float float16v;

typedef const u32 __attribute__((address_space(1))) gu32;
typedef u32 __attribute__((address_space(3))) lu32;

__device__ __forceinline__ u16 f2b(float f) {
  __hip_bfloat16 h = __float2bfloat16(f);
  return *reinterpret_cast<u16*>(&h);
}

// async global->LDS, 16B per lane; LDS dest = wave-uniform base + lane*16
__device__ __forceinline__ void gld16(const void* g, void* l) {
  __builtin_amdgcn_global_load_lds((gu32*)g, (lu32*)l, 16, 0, 0);
}

// ---------------- adj fp32 -> bf16 ----------------
__global__ __launch_bounds__(256) void k_cvt(const float* __restrict__ a, u16* __restrict__ o) {
  int t = blockIdx.x * 256 + threadIdx.x;
  float4 v0 = ((const float4*)a)[2 * t];
  float4 v1 = ((const float4*)a)[2 * t + 1];
  u16 r[8];
  r[0] = f2b(v0.x); r[1] = f2b(v0.y); r[2] = f2b(v0.z); r[3] = f2b(v0.w);
  r[4] = f2b(v1.x); r[5] = f2b(v1.y); r[6] = f2b(v1.z); r[7] = f2b(v1.w);
  ((uint4*)o)[t] = *(const uint4*)r;
}

// ---------------- mask + stats zero (fp32 in, fp32 out + bf16 H i-major) ----------------
__global__ __launch_bounds__(256) void k_mask(
    const float* __restrict__ x, const float* __restrict__ msk, const float* __restrict__ nz,
    u16* __restrict__ H, float* __restrict__ oxm, float* __restrict__ omask, float* __restrict__ ST)
{
  int t = blockIdx.x * 256 + threadIdx.x;
  if (blockIdx.x == 0) {
#pragma unroll
    for (int k = 0; k < 10; ++k) ST[threadIdx.x + k * 256] = 0.f;
  }
  float xv[8], mv[8], nv[8], rv[8];
  *(float4*)&xv[0] = ((const float4*)x)[2 * t];
  *(float4*)&xv[4] = ((const float4*)x)[2 * t + 1];
  *(float4*)&mv[0] = ((const float4*)msk)[2 * t];
  *(float4*)&mv[4] = ((const float4*)msk)[2 * t + 1];
  *(float4*)&nv[0] = ((const float4*)nz)[2 * t];
  *(float4*)&nv[4] = ((const float4*)nz)[2 * t + 1];
  u16 res[8];
#pragma unroll
  for (int j = 0; j < 8; ++j) {
    rv[j] = xv[j] * (1.f - mv[j]) + nv[j] * mv[j];
    res[j] = f2b(rv[j]);
  }
  ((uint4*)H)[t] = *(const uint4*)res;
  ((float4*)oxm)[2 * t]     = *(const float4*)&rv[0];
  ((float4*)oxm)[2 * t + 1] = *(const float4*)&rv[4];
  ((float4*)omask)[2 * t]     = *(const float4*)&mv[0];
  ((float4*)omask)[2 * t + 1] = *(const float4*)&mv[4];
}

// ---------------- small matmul: Tc = chunked( W^T @ H^T ) ----------------
// Tt[d][i] = sum_e W[e][d] * H[i][e]; Tc layout: [k-chunk kc=i/8][d][8 elems]
// MODE 0: Hin = H[i][e] bf16 (layer 0)
// MODE 1: BN-fused: read ACTt[d][i] fp32 + stats of PREVIOUS layer, apply sc*x+sh inline
// MODE 2: MODE 1 + write o_enc[i][d] fp32 (encoder->decoder boundary)
template <int MODE>
__global__ __launch_bounds__(256) void k_mm1(
    const u16* __restrict__ Hin, const float* __restrict__ ACTt,
    const float* __restrict__ STp, const float* __restrict__ gamma, const float* __restrict__ beta,
    const float* __restrict__ W, u16* __restrict__ Tc, float* __restrict__ oenc)
{
  __shared__ __align__(16) u16 Wl[128 * 136]; // [d][e], pad
  __shared__ __align__(16) u16 Hl[128 * 136]; // [i][e], pad
  const int tid = threadIdx.x;
  const int w = tid >> 6, lane = tid & 63;
  const int ln = lane & 15, quad = lane >> 4;
  const int i0 = blockIdx.x * 128;

#pragma unroll
  for (int it = 0; it < 16; ++it) { // stage W transposed, cvt fp32->bf16 (4096 float4s)
    int idx4 = (it * 256 + tid) * 4;
    int e = idx4 >> 7, d0 = idx4 & 127;
    float4 v = *(const float4*)(W + idx4);
    Wl[(d0 + 0) * 136 + e] = f2b(v.x);
    Wl[(d0 + 1) * 136 + e] = f2b(v.y);
    Wl[(d0 + 2) * 136 + e] = f2b(v.z);
    Wl[(d0 + 3) * 136 + e] = f2b(v.w);
  }
  if (MODE == 0) {
#pragma unroll
    for (int it = 0; it < 8; ++it) { // H[i][e] rows -> Hl[i][e] (2048 vec8 chunks)
      int chunk = tid + it * 256;
      int r = chunk >> 4, c8 = (chunk & 15) * 8;
      uint4 v = *(const uint4*)(Hin + (size_t)(i0 + r) * 128 + c8);
      *(uint4*)(&Hl[r * 136 + c8]) = v;
    }
  } else {
#pragma unroll
    for (int it = 0; it < 8; ++it) { // ACTt[e][i] fp32 -> BN -> transpose into Hl[i][e]
      int tmp = it * 256 + tid;      // 2048 chunks: e = tmp>>4 in [0,128)
      int e = tmp >> 4, i8 = (tmp & 15) * 8;
      float mu = STp[e] * (1.f / 8192.f);
      float var = STp[128 + e] * (1.f / 8192.f) - mu * mu;
      float sc = gamma[e] * rsqrtf(var + 1e-5f);
      float sh = beta[e] - mu * sc;
      const float* src = ACTt + (size_t)e * 8192 + i0 + i8;
      float4 v0 = *(const float4*)src;
      float4 v1 = *(const float4*)(src + 4);
      float r[8] = {v0.x, v0.y, v0.z, v0.w, v1.x, v1.y, v1.z, v1.w};
#pragma unroll
      for (int j = 0; j < 8; ++j) {
        r[j] = r[j] * sc + sh;
        Hl[(i8 + j) * 136 + e] = f2b(r[j]);
      }
      if (MODE == 2) {
#pragma unroll
        for (int j = 0; j < 8; ++j) oenc[(size_t)(i0 + i8 + j) * 128 + e] = r[j];
      }
    }
  }
  __syncthreads();

  float4v acc[2][8] = {};
#pragma unroll
  for (int ks = 0; ks < 4; ++ks) {
    short8 a[2], b[8];
#pragma unroll
    for (int r = 0; r < 2; ++r)
      a[r] = *(const short8*)&Wl[(w * 32 + r * 16 + ln) * 136 + ks * 32 + quad * 8];
#pragma unroll
    for (int c = 0; c < 8; ++c)
      b[c] = *(const short8*)&Hl[(c * 16 + ln) * 136 + ks * 32 + quad * 8];
#pragma unroll
    for (int r = 0; r < 2; ++r)
#pragma unroll
      for (int c = 0; c < 8; ++c)
        acc[r][c] = __builtin_amdgcn_mfma_f32_16x16x32_bf16(a[r], b[c], acc[r][c], 0, 0, 0);
  }
#pragma unroll
  for (int r = 0; r < 2; ++r)
#pragma unroll
    for (int c = 0; c < 8; ++c)
#pragma unroll
      for (int g = 0; g < 4; ++g) {
        int d = w * 32 + r * 16 + quad * 4 + g;   // C/D: row = quad*4+reg
        int i = i0 + c * 16 + ln;                 // C/D: col = lane&15
        Tc[((size_t)(i >> 3) * 128 + d) * 8 + (i & 7)] = f2b(acc[r][c][g]);
      }
}

// ---------------- big matmul (transposed): PB[seg][d][i] partial of OUT^T ----------------
// A = Tt (LDS, staged per 256-k sub-seg), B = adj rows (direct per-lane global loads)
// block: 4 waves as 2(d)x2(i), tile 128(d) x 128(i), KSEG=2048 (split-K 4), grid 256
// invariants vs split-K-8 version: adj bytes/block (512 KB), MFMA/block (2048),
// LDS A-reads/block (1024, reuse 0.5) all unchanged; PB partial traffic halves.
__global__ __launch_bounds__(256, 1) void k_gemm(
    const u16* __restrict__ adjB, const u16* __restrict__ Tc, float* __restrict__ PB)
{
  __shared__ __align__(16) u16 Al[2][32 * 128 * 8];  // 2 x 64 KB, chunked [lc][d][8]
  const int tid = threadIdx.x;
  const int w = tid >> 6, lane = tid & 63;
  const int lrow = lane & 31, lhalf = lane >> 5;
  const int wd = w >> 1, wi = w & 1;
  const int nt = blockIdx.x >> 2, seg = blockIdx.x & 3;
  const int i0 = nt * 128;

  // B pointers: wave covers i in [i0+wi*64, +64); frag rows are adj rows (k-contig)
  const u16* bp0 = adjB + (size_t)(i0 + wi * 64 + lrow) * 8192 + seg * 2048 + lhalf * 8;
  const u16* bp1 = bp0 + (size_t)32 * 8192;

  float16v acc[2][2] = {};

  auto stage = [&](int p, int ss) {
    const u16* src = Tc + ((size_t)(seg * 256 + ss * 32) * 128 + tid) * 8;
    u16* dst = &Al[p][tid * 8];
#pragma unroll
    for (int c = 0; c < 16; ++c)
      gld16(src + c * 2048, dst + c * 2048);   // fully coalesced 4 KB per call
  };

  auto compute = [&](int p) {
#pragma unroll 4
    for (int t = 0; t < 16; ++t) {
      short8 b0 = *(const short8*)(bp0 + t * 16);
      short8 b1 = *(const short8*)(bp1 + t * 16);
      short8 a0 = *(const short8*)&Al[p][((t * 2 + lhalf) * 128 + wd * 64 + lrow) * 8];
      short8 a1 = *(const short8*)&Al[p][((t * 2 + lhalf) * 128 + wd * 64 + 32 + lrow) * 8];
      acc[0][0] = __builtin_amdgcn_mfma_f32_32x32x16_bf16(a0, b0, acc[0][0], 0, 0, 0);
      acc[0][1] = __builtin_amdgcn_mfma_f32_32x32x16_bf16(a0, b1, acc[0][1], 0, 0, 0);
      acc[1][0] = __builtin_amdgcn_mfma_f32_32x32x16_bf16(a1, b0, acc[1][0], 0, 0, 0);
      acc[1][1] = __builtin_amdgcn_mfma_f32_32x32x16_bf16(a1, b1, acc[1][1], 0, 0, 0);
    }
    bp0 += 256; bp1 += 256;
  };

  stage(0, 0);
  __syncthreads();
#pragma unroll
  for (int ss = 0; ss < 8; ++ss) {
    if (ss < 7) stage((ss & 1) ^ 1, ss + 1);
    compute(ss & 1);
    __syncthreads();
  }

  // epilogue: C/D 32x32 layout: col(i)=lane&31, row(d)=(g&3)+8*(g>>2)+4*(lane>>5)
  const int ib = i0 + wi * 64 + lrow;
#pragma unroll
  for (int dm = 0; dm < 2; ++dm)
#pragma unroll
    for (int nb = 0; nb < 2; ++nb)
#pragma unroll
      for (int g = 0; g < 16; ++g) {
        int d = wd * 64 + dm * 32 + (g & 3) + 8 * (g >> 2) + 4 * lhalf;
        PB[((size_t)seg * 128 + d) * 8192 + ib + nb * 32] = acc[dm][nb][g];
      }
}

// ---------------- reduce partials + bias + prelu (+stats) ----------------
// grid 256: blockIdx = d*2 + half; row-major everything (coalesced)
template <bool LAST>
__global__ __launch_bounds__(256) void k_red(
    const float* __restrict__ PB, const float* __restrict__ bias, const float* __restrict__ alphaP,
    float* __restrict__ ACTt, float* __restrict__ ST, float* __restrict__ outL)
{
  const int d = blockIdx.x >> 1, half = blockIdx.x & 1;
  const int tid = threadIdx.x;
  const float bb = bias[d], alpha = alphaP[0];
  const float* pb = PB + (size_t)d * 8192 + half * 4096;
  float s1 = 0.f, s2 = 0.f;
#pragma unroll
  for (int it = 0; it < 4; ++it) {
    int idx = it * 1024 + tid * 4;
    float4 v = *(const float4*)(pb + idx);
#pragma unroll
    for (int s = 1; s < 4; ++s) {
      float4 u = *(const float4*)(pb + (size_t)s * 1048576 + idx);
      v.x += u.x; v.y += u.y; v.z += u.z; v.w += u.w;
    }
    float r[4];
    const float* vp = (const float*)&v;
#pragma unroll
    for (int j = 0; j < 4; ++j) {
      float u = vp[j] + bb;
      r[j] = (u >= 0.f) ? u : alpha * u;
    }
    if (LAST) {
      int i = half * 4096 + idx;
#pragma unroll
      for (int j = 0; j < 4; ++j) outL[(size_t)(i + j) * 128 + d] = r[j];
    } else {
      *(float4*)(ACTt + (size_t)d * 8192 + half * 4096 + idx) = *(const float4*)r;
#pragma unroll
      for (int j = 0; j < 4; ++j) { s1 += r[j]; s2 += r[j] * r[j]; }
    }
  }
  if (!LAST) {
#pragma unroll
    for (int off = 1; off < 64; off <<= 1) {
      s1 += __shfl_xor(s1, off);
      s2 += __shfl_xor(s2, off);
    }
    __shared__ float red[8];
    if ((tid & 63) == 0) { red[(tid >> 6) * 2] = s1; red[(tid >> 6) * 2 + 1] = s2; }
    __syncthreads();
    if (tid == 0) {
      atomicAdd(ST + d, red[0] + red[2] + red[4] + red[6]);
      atomicAdd(ST + 128 + d, red[1] + red[3] + red[5] + red[7]);
    }
  }
}

extern "C" void kernel_launch(void* const* d_in, const int* in_sizes, int n_in,
                              void* d_out, int out_size, void* d_ws, size_t ws_size,
                              hipStream_t stream)
{
  const float* x     = (const float*)d_in[0];
  const float* adj   = (const float*)d_in[1];
  const float* msk   = (const float*)d_in[2];
  const float* nz    = (const float*)d_in[3];
  const float* encW  = (const float*)d_in[4];
  const float* encB  = (const float*)d_in[5];
  const float* encA  = (const float*)d_in[6];
  const float* encG  = (const float*)d_in[7];
  const float* encBe = (const float*)d_in[8];
  const float* decW  = (const float*)d_in[9];
  const float* decB  = (const float*)d_in[10];
  const float* decA  = (const float*)d_in[11];
  const float* decG  = (const float*)d_in[12];
  const float* decBe = (const float*)d_in[13];

  char* ws = (char*)d_ws;
  u16*   adjB = (u16*)ws;                         // 128 MB bf16 adj
  u16*   Tc   = (u16*)(ws + 134217728ull);        // 2 MB chunked T^T
  u16*   H    = (u16*)(ws + 138412032ull);        // 2 MB bf16 [8192][128] (layer 0)
  float* ACTt = (float*)(ws + 140509184ull);      // 4 MB fp32 [128][8192]
  float* PB   = (float*)(ws + 144703488ull);      // 16 MB fp32 [4][128][8192]
  float* ST   = (float*)(ws + 178257920ull);      // 10 KB stats

  float* out   = (float*)d_out;
  float* o_xm  = out;
  float* o_enc = out + 1048576;
  float* o_dec = out + 2097152;
  float* o_msk = out + 3145728;

  k_cvt<<<32768, 256, 0, stream>>>(adj, adjB);
  k_mask<<<512, 256, 0, stream>>>(x, msk, nz, H, o_xm, o_msk, ST);

  for (int l = 0; l < 10; ++l) {
    bool e = l < 5;
    int li = e ? l : l - 5;
    const float* W  = (e ? encW : decW) + li * 16384;
    const float* bb = (e ? encB : decB) + li * 128;
    const float* al = (e ? encA : decA) + li;
    float* st = ST + l * 256;

    if (l == 0) {
      k_mm1<0><<<64, 256, 0, stream>>>(H, nullptr, nullptr, nullptr, nullptr, W, Tc, nullptr);
    } else {
      int pl = l - 1;
      bool pe = pl < 5;
      int pli = pe ? pl : pl - 5;
      const float* pg = (pe ? encG : decG) + pli * 128;
      const float* pbeta = (pe ? encBe : decBe) + pli * 128;
      const float* pst = ST + pl * 256;
      if (l == 5) k_mm1<2><<<64, 256, 0, stream>>>(nullptr, ACTt, pst, pg, pbeta, W, Tc, o_enc);
      else        k_mm1<1><<<64, 256, 0, stream>>>(nullptr, ACTt, pst, pg, pbeta, W, Tc, nullptr);
    }

    k_gemm<<<256, 256, 0, stream>>>(adjB, Tc, PB);

    if (l == 9) {
      k_red<true><<<256, 256, 0, stream>>>(PB, bb, al, nullptr, nullptr, o_dec);
    } else {
      k_red<false><<<256, 256, 0, stream>>>(PB, bb, al, ACTt, st, nullptr);
    }
  }
}

// Round 3
// 934.652 us; speedup vs baseline: 1.1241x; 1.1241x over previous
//
#include <hip/hip_runtime.h>
#include <hip/hip_bf16.h>
#include <stdint.h>

typedef unsigned short u16;
typedef unsigned int u32;

typedef __attribute__((__ext_vector_type__(8))) short short8;
typedef __attribute__((__ext_vector_type__(4))) float float4v;
typedef __attribute__((__ext_vector_type__(16))) float float16v;

typedef const u32 __attribute__((address_space(1))) gu32;
typedef u32 __attribute__((address_space(3))) lu32;

__device__ __forceinline__ u16 f2b(float f) {
  __hip_bfloat16 h = __float2bfloat16(f);
  return *reinterpret_cast<u16*>(&h);
}

// async global->LDS, 16B per lane; LDS dest = wave-uniform base + lane*16
__device__ __forceinline__ void gld16(const void* g, void* l) {
  __builtin_amdgcn_global_load_lds((gu32*)g, (lu32*)l, 16, 0, 0);
}

// ---------------- adj fp32 -> bf16 ----------------
__global__ __launch_bounds__(256) void k_cvt(const float* __restrict__ a, u16* __restrict__ o) {
  int t = blockIdx.x * 256 + threadIdx.x;
  float4 v0 = ((const float4*)a)[2 * t];
  float4 v1 = ((const float4*)a)[2 * t + 1];
  u16 r[8];
  r[0] = f2b(v0.x); r[1] = f2b(v0.y); r[2] = f2b(v0.z); r[3] = f2b(v0.w);
  r[4] = f2b(v1.x); r[5] = f2b(v1.y); r[6] = f2b(v1.z); r[7] = f2b(v1.w);
  ((uint4*)o)[t] = *(const uint4*)r;
}

// ---------------- mask + stats zero (fp32 in, fp32 out + bf16 H i-major) ----------------
__global__ __launch_bounds__(256) void k_mask(
    const float* __restrict__ x, const float* __restrict__ msk, const float* __restrict__ nz,
    u16* __restrict__ H, float* __restrict__ oxm, float* __restrict__ omask, float* __restrict__ ST)
{
  int t = blockIdx.x * 256 + threadIdx.x;
  if (blockIdx.x == 0) {
#pragma unroll
    for (int k = 0; k < 10; ++k) ST[threadIdx.x + k * 256] = 0.f;
  }
  float xv[8], mv[8], nv[8], rv[8];
  *(float4*)&xv[0] = ((const float4*)x)[2 * t];
  *(float4*)&xv[4] = ((const float4*)x)[2 * t + 1];
  *(float4*)&mv[0] = ((const float4*)msk)[2 * t];
  *(float4*)&mv[4] = ((const float4*)msk)[2 * t + 1];
  *(float4*)&nv[0] = ((const float4*)nz)[2 * t];
  *(float4*)&nv[4] = ((const float4*)nz)[2 * t + 1];
  u16 res[8];
#pragma unroll
  for (int j = 0; j < 8; ++j) {
    rv[j] = xv[j] * (1.f - mv[j]) + nv[j] * mv[j];
    res[j] = f2b(rv[j]);
  }
  ((uint4*)H)[t] = *(const uint4*)res;
  ((float4*)oxm)[2 * t]     = *(const float4*)&rv[0];
  ((float4*)oxm)[2 * t + 1] = *(const float4*)&rv[4];
  ((float4*)omask)[2 * t]     = *(const float4*)&mv[0];
  ((float4*)omask)[2 * t + 1] = *(const float4*)&mv[4];
}

// ---------------- small matmul: Tc = chunked( W^T @ H^T ) ----------------
// Tt[d][i] = sum_e W[e][d] * H[i][e]; Tc layout: [k-chunk kc=i/8][d][8 elems]
// MODE 0: Hin = H[i][e] bf16 (layer 0)
// MODE 1: BN-fused: read ACTt[d][i] fp32 + stats of PREVIOUS layer, apply sc*x+sh inline
// MODE 2: MODE 1 + write o_enc[i][d] fp32 (encoder->decoder boundary)
template <int MODE>
__global__ __launch_bounds__(256) void k_mm1(
    const u16* __restrict__ Hin, const float* __restrict__ ACTt,
    const float* __restrict__ STp, const float* __restrict__ gamma, const float* __restrict__ beta,
    const float* __restrict__ W, u16* __restrict__ Tc, float* __restrict__ oenc)
{
  __shared__ __align__(16) u16 Wl[128 * 136]; // [d][e], pad
  __shared__ __align__(16) u16 Hl[128 * 136]; // [i][e], pad
  const int tid = threadIdx.x;
  const int w = tid >> 6, lane = tid & 63;
  const int ln = lane & 15, quad = lane >> 4;
  const int i0 = blockIdx.x * 128;

#pragma unroll
  for (int it = 0; it < 16; ++it) { // stage W transposed, cvt fp32->bf16 (4096 float4s)
    int idx4 = (it * 256 + tid) * 4;
    int e = idx4 >> 7, d0 = idx4 & 127;
    float4 v = *(const float4*)(W + idx4);
    Wl[(d0 + 0) * 136 + e] = f2b(v.x);
    Wl[(d0 + 1) * 136 + e] = f2b(v.y);
    Wl[(d0 + 2) * 136 + e] = f2b(v.z);
    Wl[(d0 + 3) * 136 + e] = f2b(v.w);
  }
  if (MODE == 0) {
#pragma unroll
    for (int it = 0; it < 8; ++it) { // H[i][e] rows -> Hl[i][e] (2048 vec8 chunks)
      int chunk = tid + it * 256;
      int r = chunk >> 4, c8 = (chunk & 15) * 8;
      uint4 v = *(const uint4*)(Hin + (size_t)(i0 + r) * 128 + c8);
      *(uint4*)(&Hl[r * 136 + c8]) = v;
    }
  } else {
#pragma unroll
    for (int it = 0; it < 8; ++it) { // ACTt[e][i] fp32 -> BN -> transpose into Hl[i][e]
      int tmp = it * 256 + tid;      // 2048 chunks: e = tmp>>4 in [0,128)
      int e = tmp >> 4, i8 = (tmp & 15) * 8;
      float mu = STp[e] * (1.f / 8192.f);
      float var = STp[128 + e] * (1.f / 8192.f) - mu * mu;
      float sc = gamma[e] * rsqrtf(var + 1e-5f);
      float sh = beta[e] - mu * sc;
      const float* src = ACTt + (size_t)e * 8192 + i0 + i8;
      float4 v0 = *(const float4*)src;
      float4 v1 = *(const float4*)(src + 4);
      float r[8] = {v0.x, v0.y, v0.z, v0.w, v1.x, v1.y, v1.z, v1.w};
#pragma unroll
      for (int j = 0; j < 8; ++j) {
        r[j] = r[j] * sc + sh;
        Hl[(i8 + j) * 136 + e] = f2b(r[j]);
      }
      if (MODE == 2) {
#pragma unroll
        for (int j = 0; j < 8; ++j) oenc[(size_t)(i0 + i8 + j) * 128 + e] = r[j];
      }
    }
  }
  __syncthreads();

  float4v acc[2][8] = {};
#pragma unroll
  for (int ks = 0; ks < 4; ++ks) {
    short8 a[2], b[8];
#pragma unroll
    for (int r = 0; r < 2; ++r)
      a[r] = *(const short8*)&Wl[(w * 32 + r * 16 + ln) * 136 + ks * 32 + quad * 8];
#pragma unroll
    for (int c = 0; c < 8; ++c)
      b[c] = *(const short8*)&Hl[(c * 16 + ln) * 136 + ks * 32 + quad * 8];
#pragma unroll
    for (int r = 0; r < 2; ++r)
#pragma unroll
      for (int c = 0; c < 8; ++c)
        acc[r][c] = __builtin_amdgcn_mfma_f32_16x16x32_bf16(a[r], b[c], acc[r][c], 0, 0, 0);
  }
#pragma unroll
  for (int r = 0; r < 2; ++r)
#pragma unroll
    for (int c = 0; c < 8; ++c)
#pragma unroll
      for (int g = 0; g < 4; ++g) {
        int d = w * 32 + r * 16 + quad * 4 + g;   // C/D: row = quad*4+reg
        int i = i0 + c * 16 + ln;                 // C/D: col = lane&15
        Tc[((size_t)(i >> 3) * 128 + d) * 8 + (i & 7)] = f2b(acc[r][c][g]);
      }
}

// ---------------- big matmul (transposed): PB[seg][d][i] partial of OUT^T ----------------
// A = Tt (LDS, staged per 128-k sub-seg), B = adj rows (direct per-lane global loads)
// block: 4 waves as 1(d)x4(i) -> ZERO B duplication; tile 128(d) x 128(i), KSEG=1024
// split-K 8, grid 512; LDS 2x32KB -> 2 blocks/CU -> 2 waves/SIMD (latency hiding)
__global__ __launch_bounds__(256, 2) void k_gemm(
    const u16* __restrict__ adjB, const u16* __restrict__ Tc, float* __restrict__ PB)
{
  __shared__ __align__(16) u16 Al[2][16 * 128 * 8];  // 2 x 32 KB, chunked [lc][d][8]
  const int tid = threadIdx.x;
  const int w = tid >> 6, lane = tid & 63;
  const int lrow = lane & 31, lhalf = lane >> 5;
  const int nt = blockIdx.x >> 3, seg = blockIdx.x & 7;
  const int i0 = nt * 128;

  // B pointer: wave w covers i in [i0+w*32, +32); frag rows are adj rows (k-contig)
  const u16* bp = adjB + (size_t)(i0 + w * 32 + lrow) * 8192 + seg * 1024 + lhalf * 8;

  float16v acc[4] = {};

  auto stage = [&](int p, int ss) {
    // sub-seg = 16 k-chunks (128 k) x 128 d x 8 elems = 32 KB; 8 gld16/thread
    const u16* src = Tc + ((size_t)(seg * 128 + ss * 16) * 128 + tid) * 8;
    u16* dst = &Al[p][tid * 8];
#pragma unroll
    for (int c = 0; c < 8; ++c)
      gld16(src + c * 2048, dst + c * 2048);   // fully coalesced 4 KB per call
  };

  auto compute = [&](int p) {
#pragma unroll
    for (int t = 0; t < 8; ++t) {
      short8 b = *(const short8*)(bp + t * 16);
      short8 a0 = *(const short8*)&Al[p][((t * 2 + lhalf) * 128 + lrow) * 8];
      short8 a1 = *(const short8*)&Al[p][((t * 2 + lhalf) * 128 + 32 + lrow) * 8];
      short8 a2 = *(const short8*)&Al[p][((t * 2 + lhalf) * 128 + 64 + lrow) * 8];
      short8 a3 = *(const short8*)&Al[p][((t * 2 + lhalf) * 128 + 96 + lrow) * 8];
      acc[0] = __builtin_amdgcn_mfma_f32_32x32x16_bf16(a0, b, acc[0], 0, 0, 0);
      acc[1] = __builtin_amdgcn_mfma_f32_32x32x16_bf16(a1, b, acc[1], 0, 0, 0);
      acc[2] = __builtin_amdgcn_mfma_f32_32x32x16_bf16(a2, b, acc[2], 0, 0, 0);
      acc[3] = __builtin_amdgcn_mfma_f32_32x32x16_bf16(a3, b, acc[3], 0, 0, 0);
    }
    bp += 128;
  };

  stage(0, 0);
  __syncthreads();
#pragma unroll
  for (int ss = 0; ss < 8; ++ss) {
    if (ss < 7) stage((ss & 1) ^ 1, ss + 1);
    compute(ss & 1);
    __syncthreads();
  }

  // epilogue: C/D 32x32 layout: col(i)=lane&31, row(d)=(g&3)+8*(g>>2)+4*(lane>>5)
  const int ib = i0 + w * 32 + lrow;
#pragma unroll
  for (int dm = 0; dm < 4; ++dm)
#pragma unroll
    for (int g = 0; g < 16; ++g) {
      int d = dm * 32 + (g & 3) + 8 * (g >> 2) + 4 * lhalf;
      PB[((size_t)seg * 128 + d) * 8192 + ib] = acc[dm][g];
    }
}

// ---------------- reduce partials + bias + prelu (+stats) ----------------
// grid 256: blockIdx = d*2 + half; row-major everything (coalesced)
template <bool LAST>
__global__ __launch_bounds__(256) void k_red(
    const float* __restrict__ PB, const float* __restrict__ bias, const float* __restrict__ alphaP,
    float* __restrict__ ACTt, float* __restrict__ ST, float* __restrict__ outL)
{
  const int d = blockIdx.x >> 1, half = blockIdx.x & 1;
  const int tid = threadIdx.x;
  const float bb = bias[d], alpha = alphaP[0];
  const float* pb = PB + (size_t)d * 8192 + half * 4096;
  float s1 = 0.f, s2 = 0.f;
#pragma unroll
  for (int it = 0; it < 4; ++it) {
    int idx = it * 1024 + tid * 4;
    float4 v = *(const float4*)(pb + idx);
#pragma unroll
    for (int s = 1; s < 8; ++s) {
      float4 u = *(const float4*)(pb + (size_t)s * 1048576 + idx);
      v.x += u.x; v.y += u.y; v.z += u.z; v.w += u.w;
    }
    float r[4];
    const float* vp = (const float*)&v;
#pragma unroll
    for (int j = 0; j < 4; ++j) {
      float u = vp[j] + bb;
      r[j] = (u >= 0.f) ? u : alpha * u;
    }
    if (LAST) {
      int i = half * 4096 + idx;
#pragma unroll
      for (int j = 0; j < 4; ++j) outL[(size_t)(i + j) * 128 + d] = r[j];
    } else {
      *(float4*)(ACTt + (size_t)d * 8192 + half * 4096 + idx) = *(const float4*)r;
#pragma unroll
      for (int j = 0; j < 4; ++j) { s1 += r[j]; s2 += r[j] * r[j]; }
    }
  }
  if (!LAST) {
#pragma unroll
    for (int off = 1; off < 64; off <<= 1) {
      s1 += __shfl_xor(s1, off);
      s2 += __shfl_xor(s2, off);
    }
    __shared__ float red[8];
    if ((tid & 63) == 0) { red[(tid >> 6) * 2] = s1; red[(tid >> 6) * 2 + 1] = s2; }
    __syncthreads();
    if (tid == 0) {
      atomicAdd(ST + d, red[0] + red[2] + red[4] + red[6]);
      atomicAdd(ST + 128 + d, red[1] + red[3] + red[5] + red[7]);
    }
  }
}

extern "C" void kernel_launch(void* const* d_in, const int* in_sizes, int n_in,
                              void* d_out, int out_size, void* d_ws, size_t ws_size,
                              hipStream_t stream)
{
  const float* x     = (const float*)d_in[0];
  const float* adj   = (const float*)d_in[1];
  const float* msk   = (const float*)d_in[2];
  const float* nz    = (const float*)d_in[3];
  const float* encW  = (const float*)d_in[4];
  const float* encB  = (const float*)d_in[5];
  const float* encA  = (const float*)d_in[6];
  const float* encG  = (const float*)d_in[7];
  const float* encBe = (const float*)d_in[8];
  const float* decW  = (const float*)d_in[9];
  const float* decB  = (const float*)d_in[10];
  const float* decA  = (const float*)d_in[11];
  const float* decG  = (const float*)d_in[12];
  const float* decBe = (const float*)d_in[13];

  char* ws = (char*)d_ws;
  u16*   adjB = (u16*)ws;                         // 128 MB bf16 adj
  u16*   Tc   = (u16*)(ws + 134217728ull);        // 2 MB chunked T^T
  u16*   H    = (u16*)(ws + 138412032ull);        // 2 MB bf16 [8192][128] (layer 0)
  float* ACTt = (float*)(ws + 140509184ull);      // 4 MB fp32 [128][8192]
  float* PB   = (float*)(ws + 144703488ull);      // 32 MB fp32 [8][128][8192]
  float* ST   = (float*)(ws + 178257920ull);      // 10 KB stats

  float* out   = (float*)d_out;
  float* o_xm  = out;
  float* o_enc = out + 1048576;
  float* o_dec = out + 2097152;
  float* o_msk = out + 3145728;

  k_cvt<<<32768, 256, 0, stream>>>(adj, adjB);
  k_mask<<<512, 256, 0, stream>>>(x, msk, nz, H, o_xm, o_msk, ST);

  for (int l = 0; l < 10; ++l) {
    bool e = l < 5;
    int li = e ? l : l - 5;
    const float* W  = (e ? encW : decW) + li * 16384;
    const float* bb = (e ? encB : decB) + li * 128;
    const float* al = (e ? encA : decA) + li;
    float* st = ST + l * 256;

    if (l == 0) {
      k_mm1<0><<<64, 256, 0, stream>>>(H, nullptr, nullptr, nullptr, nullptr, W, Tc, nullptr);
    } else {
      int pl = l - 1;
      bool pe = pl < 5;
      int pli = pe ? pl : pl - 5;
      const float* pg = (pe ? encG : decG) + pli * 128;
      const float* pbeta = (pe ? encBe : decBe) + pli * 128;
      const float* pst = ST + pl * 256;
      if (l == 5) k_mm1<2><<<64, 256, 0, stream>>>(nullptr, ACTt, pst, pg, pbeta, W, Tc, o_enc);
      else        k_mm1<1><<<64, 256, 0, stream>>>(nullptr, ACTt, pst, pg, pbeta, W, Tc, nullptr);
    }

    k_gemm<<<512, 256, 0, stream>>>(adjB, Tc, PB);

    if (l == 9) {
      k_red<true><<<256, 256, 0, stream>>>(PB, bb, al, nullptr, nullptr, o_dec);
    } else {
      k_red<false><<<256, 256, 0, stream>>>(PB, bb, al, ACTt, st, nullptr);
    }
  }
}